// Round 10
// baseline (263.662 us; speedup 1.0000x reference)
//
#include <hip/hip_runtime.h>

#define CAP   64   // dense per-node capacity (Poisson(16): P(>64) ~ 1e-21)
#define NREP  8    // counter replicas (shortens per-address atomic chains 8x)
#define CAPR  16   // per-replica sub-bucket capacity (Poisson(2): P(>16) ~ 1e-10)

typedef __attribute__((ext_vector_type(8))) short bf16x8;
typedef __attribute__((ext_vector_type(4))) float f32x4;

__device__ __forceinline__ unsigned short f2bf(float f) {
    unsigned u = __builtin_bit_cast(unsigned, f);
    u += 0x7fffu + ((u >> 16) & 1u);   // round-to-nearest-even
    return (unsigned short)(u >> 16);
}
__device__ __forceinline__ float bf2f(unsigned short h) {
    unsigned u = ((unsigned)h) << 16;
    return __builtin_bit_cast(float, u);
}

// async 16B global->LDS copy (lds dest must be wave-uniform; HW adds lane*16)
__device__ __forceinline__ void gload_lds16(const void* g, void* lds) {
    __builtin_amdgcn_global_load_lds(
        (const __attribute__((address_space(1))) void*)g,
        (__attribute__((address_space(3))) void*)lds, 16, 0, 0);
}

// R9: replicated counters. cnt8[d][r] (r = blockIdx&7): per-address atomic chains
// drop from ~deg (tail ~45, cross-XCD serialized) to ~deg/8 (tail <=16).
// Straight-line 4 atomics + 4 dependent stores, no pass loop.
__global__ __launch_bounds__(256)
void fill_bucket_kernel(const int* __restrict__ src, const int* __restrict__ dst,
                        int* __restrict__ cnt8, unsigned short* __restrict__ slot8, int E) {
    int t  = blockIdx.x * 256 + threadIdx.x;
    int e0 = t * 4;
    if (e0 >= E) return;
    const int r = blockIdx.x & (NREP - 1);
    int4 s4, d4;
    if (e0 + 4 <= E) {
        s4 = *reinterpret_cast<const int4*>(src + e0);
        d4 = *reinterpret_cast<const int4*>(dst + e0);
    } else {
        int rr = E - e0;
        s4.x = src[e0];                   d4.x = dst[e0];
        s4.y = (rr > 1) ? src[e0 + 1] : 0; d4.y = (rr > 1) ? dst[e0 + 1] : -1;
        s4.z = (rr > 2) ? src[e0 + 2] : 0; d4.z = (rr > 2) ? dst[e0 + 2] : -1;
        s4.w = 0;                          d4.w = -1;
    }
    if (d4.x >= 0) {
        int q = atomicAdd(&cnt8[(size_t)d4.x * NREP + r], 1);
        if (q < CAPR) slot8[(size_t)d4.x * (NREP * CAPR) + r * CAPR + q] = (unsigned short)s4.x;
    }
    if (d4.y >= 0) {
        int q = atomicAdd(&cnt8[(size_t)d4.y * NREP + r], 1);
        if (q < CAPR) slot8[(size_t)d4.y * (NREP * CAPR) + r * CAPR + q] = (unsigned short)s4.y;
    }
    if (d4.z >= 0) {
        int q = atomicAdd(&cnt8[(size_t)d4.z * NREP + r], 1);
        if (q < CAPR) slot8[(size_t)d4.z * (NREP * CAPR) + r * CAPR + q] = (unsigned short)s4.z;
    }
    if (d4.w >= 0) {
        int q = atomicAdd(&cnt8[(size_t)d4.w * NREP + r], 1);
        if (q < CAPR) slot8[(size_t)d4.w * (NREP * CAPR) + r * CAPR + q] = (unsigned short)s4.w;
    }
}

// One wave per node: merge the 8 sub-buckets (8x16 entries) into a dense row of
// deg entries + deg[node]. Lane l holds entries 2l,2l+1 (group r = l>>3);
// sub-counts prefix-scanned across lanes 0..7 via shfl.
__global__ __launch_bounds__(256)
void compact_kernel(const int* __restrict__ cnt8, const unsigned short* __restrict__ slot8,
                    unsigned short* __restrict__ dense, int* __restrict__ deg, int N) {
    const int node = (int)(((size_t)blockIdx.x * blockDim.x + threadIdx.x) >> 6);
    const int l    = threadIdx.x & 63;
    if (node >= N) return;

    int cr = 0;
    if (l < NREP) {
        cr = cnt8[(size_t)node * NREP + l];
        if (cr > CAPR) cr = CAPR;
    }
    int pre = cr;                       // inclusive prefix over lanes 0..7
    #pragma unroll
    for (int o = 1; o < NREP; o <<= 1) {
        int v = __shfl_up(pre, o, 64);
        if (l >= o) pre += v;
    }
    const int myr = l >> 3;             // group of both my entries
    const int c   = __shfl(cr, myr, 64);        // my group's sub-count
    const int b   = __shfl(pre - cr, myr, 64);  // my group's exclusive base
    int tot = __shfl(pre, NREP - 1, 64);
    if (tot > CAP) tot = CAP;

    unsigned ent = *reinterpret_cast<const unsigned*>(slot8 + (size_t)node * (NREP * CAPR) + 2 * l);
    const int q0 = 2 * (l & 7), q1 = q0 + 1;
    const int p0 = b + q0,      p1 = b + q1;
    if (q0 < c && p0 < CAP) dense[(size_t)node * CAP + p0] = (unsigned short)(ent & 0xffffu);
    if (q1 < c && p1 < CAP) dense[(size_t)node * CAP + p1] = (unsigned short)(ent >> 16);
    if (l == 0) deg[node] = tot;
}

// Split x (f32) into hi/lo bf16 pair buffers.
__global__ __launch_bounds__(256)
void split_x_kernel(const float* __restrict__ x, unsigned short* __restrict__ xhi,
                    unsigned short* __restrict__ xlo, long long total4)
{
    long long i = (long long)blockIdx.x * 256 + threadIdx.x;
    if (i >= total4) return;
    float4 v = reinterpret_cast<const float4*>(x)[i];
    float f[4] = {v.x, v.y, v.z, v.w};
    unsigned short h4[4], l4[4];
    #pragma unroll
    for (int j = 0; j < 4; j++) {
        h4[j] = f2bf(f[j]);
        l4[j] = f2bf(f[j] - bf2f(h4[j]));
    }
    reinterpret_cast<ushort4*>(xhi)[i] = make_ushort4(h4[0], h4[1], h4[2], h4[3]);
    reinterpret_cast<ushort4*>(xlo)[i] = make_ushort4(l4[0], l4[1], l4[2], l4[3]);
}

// All three layers' W prep in one launch.
__global__ __launch_bounds__(256)
void prep_w_all_kernel(const float* __restrict__ Ws0, const float* __restrict__ Wn0,
                       const float* __restrict__ Ws1, const float* __restrict__ Wn1,
                       const float* __restrict__ Ws2, const float* __restrict__ Wn2,
                       unsigned short* __restrict__ Wh0, unsigned short* __restrict__ Wl0,
                       unsigned short* __restrict__ Wh1, unsigned short* __restrict__ Wl1,
                       unsigned short* __restrict__ Wh2, unsigned short* __restrict__ Wl2)
{
    int b = blockIdx.x;
    const float *Ws, *Wn;
    unsigned short *Wthi, *Wtlo;
    int D, idx;
    if (b < 128)      { Ws = Ws0; Wn = Wn0; Wthi = Wh0; Wtlo = Wl0; D = 128; idx = b * 256 + threadIdx.x; }
    else if (b < 256) { Ws = Ws1; Wn = Wn1; Wthi = Wh1; Wtlo = Wl1; D = 128; idx = (b - 128) * 256 + threadIdx.x; }
    else              { Ws = Ws2; Wn = Wn2; Wthi = Wh2; Wtlo = Wl2; D = 64;  idx = (b - 256) * 256 + threadIdx.x; }
    int DT = 2 * D;
    if (idx >= 128 * DT) return;
    int k = idx / DT, col = idx % DT;
    float v = (col < D) ? Ws[k * D + col] : Wn[k * D + (col - D)];
    unsigned short hi = f2bf(v);
    unsigned short lo = f2bf(v - bf2f(hi));
    Wthi[col * 128 + k] = hi;
    Wtlo[col * 128 + k] = lo;
}

// hs = h @ Ws + b (f32), hn = bf16(h @ Wn). Split-product: hh*Wh + hh*Wl + hl*Wh.
// Block = 64 rows x ALL cols (A fetched once). A hi/lo staged into 32KB LDS via
// async global_load_lds (width 16). LDS nibble-XOR swizzle applied to the GLOBAL
// source (linear LDS dest) and to the ds_read address.
// MFMA layouts (gfx950 16x16x32_bf16): A: [row=l&15][k=(l>>4)*8+j]; B same with
// col=l&15 (k-contiguous both => X @ W since Wt is W^T); D: [row=(l>>4)*4+r][col=l&15].
template<int DTOT>
__global__ __launch_bounds__(256)
void mfma_dual_kernel(const unsigned short* __restrict__ hhi, const unsigned short* __restrict__ hlo,
                      const unsigned short* __restrict__ Wthi, const unsigned short* __restrict__ Wtlo,
                      const float* __restrict__ bias,
                      float* __restrict__ hs, unsigned short* __restrict__ hn, int N)
{
    constexpr int D  = DTOT / 2;
    constexpr int NT = DTOT / 64;   // 16-col tiles per wave (4 or 2)
    constexpr int MT = 4;           // 16-row tiles per wave (64 rows/block)

    __shared__ unsigned short Ahi_l[64 * 128];   // 16KB, swizzled layout
    __shared__ unsigned short Alo_l[64 * 128];   // 16KB

    const int tid = threadIdx.x;
    const int wv  = tid >> 6;
    const int l   = tid & 63;
    const int lm  = l & 15;
    const int kg  = l >> 4;
    const int block0  = blockIdx.x * 64;
    const int colbase = wv * (NT * 16);

    // ---- stage A tile (hi+lo) into LDS: 4 async 1KB copies per wave per buffer ----
    {
        const int row_l = (l >> 4);          // lane's row-within-quad
        const int col16 = l & 15;            // lane's 16B granule index
        #pragma unroll
        for (int i = 0; i < 4; i++) {
            const int ldsoff = wv * 4096 + i * 1024;            // uniform byte base
            int row = wv * 16 + i * 4 + row_l;                  // [0,64)
            int k2  = ((col16 ^ (row & 15)) << 4);              // swizzled byte offset
            int rg  = block0 + row; if (rg > N - 1) rg = N - 1; // clamp (never stored)
            gload_lds16((const char*)hhi + (size_t)rg * 256 + k2, (char*)Ahi_l + ldsoff);
            gload_lds16((const char*)hlo + (size_t)rg * 256 + k2, (char*)Alo_l + ldsoff);
        }
    }
    asm volatile("s_waitcnt vmcnt(0)" ::: "memory");
    __syncthreads();

    f32x4 acc[MT][NT];
    #pragma unroll
    for (int mt = 0; mt < MT; mt++)
        #pragma unroll
        for (int nt = 0; nt < NT; nt++)
            acc[mt][nt] = (f32x4){0.f, 0.f, 0.f, 0.f};

    const size_t bofs = (size_t)(colbase + lm) * 128 + kg * 8;

    #pragma unroll
    for (int c = 0; c < 4; c++) {          // K chunks of 32
        // B from global (W is L2-resident: 128KB shared by all blocks)
        bf16x8 bh[NT], bl[NT];
        #pragma unroll
        for (int nt = 0; nt < NT; nt++) {
            const size_t bo = bofs + (size_t)nt * 16 * 128 + c * 32;
            bh[nt] = *reinterpret_cast<const bf16x8*>(Wthi + bo);
            bl[nt] = *reinterpret_cast<const bf16x8*>(Wtlo + bo);
        }
        // A from LDS (swizzled read: granule = (kg+4c) ^ lm)
        bf16x8 ah[MT], al[MT];
        #pragma unroll
        for (int mt = 0; mt < MT; mt++) {
            const int r   = mt * 16 + lm;
            const int off = r * 128 + (((kg + 4 * c) ^ lm) << 3);  // ushort units
            ah[mt] = *reinterpret_cast<const bf16x8*>(&Ahi_l[off]);
            al[mt] = *reinterpret_cast<const bf16x8*>(&Alo_l[off]);
        }
        #pragma unroll
        for (int nt = 0; nt < NT; nt++)
            #pragma unroll
            for (int mt = 0; mt < MT; mt++) {
                acc[mt][nt] = __builtin_amdgcn_mfma_f32_16x16x32_bf16(ah[mt], bh[nt], acc[mt][nt], 0, 0, 0);
                acc[mt][nt] = __builtin_amdgcn_mfma_f32_16x16x32_bf16(ah[mt], bl[nt], acc[mt][nt], 0, 0, 0);
                acc[mt][nt] = __builtin_amdgcn_mfma_f32_16x16x32_bf16(al[mt], bh[nt], acc[mt][nt], 0, 0, 0);
            }
    }

    #pragma unroll
    for (int nt = 0; nt < NT; nt++) {
        const int col = colbase + nt * 16 + lm;
        const float bb = (col < D) ? bias[col] : 0.f;
        #pragma unroll
        for (int mt = 0; mt < MT; mt++) {
            #pragma unroll
            for (int i = 0; i < 4; i++) {
                int n = block0 + mt * 16 + kg * 4 + i;
                if (n >= N) continue;
                float v = acc[mt][nt][i];
                if (col < D) hs[(size_t)n * D + col] = v + bb;
                else         hn[(size_t)n * D + (col - D)] = f2bf(v);
            }
        }
    }
}

// One wave per dst node. Indices lane-resident (one coalesced 2B/lane load of the
// dense slot row); inner loop __shfl-broadcasts 8 indices, 8 gather loads in flight.
template<int D, bool RELU, bool SPLIT>
__global__ __launch_bounds__(256)
void gather_finish_kernel(const unsigned short* __restrict__ hn, const float* __restrict__ hs,
                          const int* __restrict__ deg_arr, const unsigned short* __restrict__ dense,
                          unsigned short* __restrict__ ohi, unsigned short* __restrict__ olo,
                          float* __restrict__ ofp, int N)
{
    const int node = (int)(((size_t)blockIdx.x * blockDim.x + threadIdx.x) >> 6);
    const int lane = threadIdx.x & 63;
    if (node >= N) return;

    int deg = deg_arr[node];
    if (deg > CAP) deg = CAP;

    // whole dense row in registers: lane i holds index i
    const int si = (int)dense[(size_t)node * CAP + lane];

    float p0 = 0.f, p1 = 0.f, q0 = 0.f, q1 = 0.f;
    float r0a = 0.f, r1a = 0.f, t0 = 0.f, t1 = 0.f;

    for (int j = 0; j < deg; j += 8) {
        unsigned u[8];
        bool ok[8];
        #pragma unroll
        for (int k = 0; k < 8; k++) {
            int jj = j + k;
            int s = __shfl(si, jj, 64);
            if (s > N - 1) s = N - 1;      // lanes >= deg hold garbage; clamp, mask below
            if (s < 0) s = 0;
            ok[k] = jj < deg;
            if constexpr (D == 128)
                u[k] = *reinterpret_cast<const unsigned*>(&hn[(size_t)s * D + lane * 2]);
            else
                u[k] = (unsigned)hn[(size_t)s * D + lane];
        }
        #pragma unroll
        for (int k = 0; k < 8; k++) {
            float f0 = ok[k] ? bf2f((unsigned short)(u[k] & 0xffffu)) : 0.f;
            if constexpr (D == 128) {
                float f1 = ok[k] ? bf2f((unsigned short)(u[k] >> 16)) : 0.f;
                switch (k & 3) {
                    case 0: p0 += f0; p1 += f1; break;
                    case 1: q0 += f0; q1 += f1; break;
                    case 2: r0a += f0; r1a += f1; break;
                    default: t0 += f0; t1 += f1; break;
                }
            } else {
                switch (k & 3) {
                    case 0: p0 += f0; break;
                    case 1: q0 += f0; break;
                    case 2: r0a += f0; break;
                    default: t0 += f0; break;
                }
            }
        }
    }
    float acc0 = (p0 + q0) + (r0a + t0);
    float acc1 = (p1 + q1) + (r1a + t1);

    const float inv = 1.0f / (float)(deg > 1 ? deg : 1);

    if constexpr (D == 128) {
        float2 s2 = *reinterpret_cast<const float2*>(&hs[(size_t)node * D + lane * 2]);
        float v0 = fmaf(acc0, inv, s2.x);
        float v1 = fmaf(acc1, inv, s2.y);
        if (RELU) { v0 = fmaxf(v0, 0.f); v1 = fmaxf(v1, 0.f); }
        if constexpr (SPLIT) {
            unsigned short h0 = f2bf(v0), h1 = f2bf(v1);
            unsigned short l0 = f2bf(v0 - bf2f(h0)), l1 = f2bf(v1 - bf2f(h1));
            *reinterpret_cast<unsigned*>(&ohi[(size_t)node * D + lane * 2]) = (unsigned)h0 | ((unsigned)h1 << 16);
            *reinterpret_cast<unsigned*>(&olo[(size_t)node * D + lane * 2]) = (unsigned)l0 | ((unsigned)l1 << 16);
        } else {
            *reinterpret_cast<float2*>(&ofp[(size_t)node * D + lane * 2]) = make_float2(v0, v1);
        }
    } else {
        float s1 = hs[(size_t)node * D + lane];
        float v = fmaf(acc0, inv, s1);
        if (RELU) v = fmaxf(v, 0.f);
        if constexpr (SPLIT) {
            unsigned short h0 = f2bf(v);
            ohi[(size_t)node * D + lane] = h0;
            olo[(size_t)node * D + lane] = f2bf(v - bf2f(h0));
        } else {
            ofp[(size_t)node * D + lane] = v;
        }
    }
}

extern "C" void kernel_launch(void* const* d_in, const int* in_sizes, int n_in,
                              void* d_out, int out_size, void* d_ws, size_t ws_size,
                              hipStream_t stream)
{
    const float* x   = (const float*)d_in[0];
    const int*   src = (const int*)d_in[1];
    const int*   dst = (const int*)d_in[2];
    const float* Ws0 = (const float*)d_in[3];
    const float* Wn0 = (const float*)d_in[4];
    const float* b0  = (const float*)d_in[5];
    const float* Ws1 = (const float*)d_in[6];
    const float* Wn1 = (const float*)d_in[7];
    const float* b1  = (const float*)d_in[8];
    const float* Ws2 = (const float*)d_in[9];
    const float* Wn2 = (const float*)d_in[10];
    const float* b2  = (const float*)d_in[11];
    float* out = (float*)d_out;

    const int N = in_sizes[0] / 128;
    const int E = in_sizes[1];

    char* ws = (char*)d_ws;
    size_t off = 0;
    auto alloc = [&](size_t bytes) -> void* {
        void* p = ws + off;
        off += (bytes + 255) & ~(size_t)255;
        return p;
    };
    int*            cnt8  = (int*)           alloc((size_t)N * NREP * 4);
    unsigned short* slot8 = (unsigned short*)alloc((size_t)N * NREP * CAPR * 2);
    unsigned short* dense = (unsigned short*)alloc((size_t)N * CAP * 2);
    int*            deg   = (int*)           alloc((size_t)N * 4);
    unsigned short* xhi   = (unsigned short*)alloc((size_t)N * 128 * 2);  // reused as h hi/lo between layers
    unsigned short* xlo   = (unsigned short*)alloc((size_t)N * 128 * 2);
    float*          hsb   = (float*)         alloc((size_t)N * 128 * 4);
    unsigned short* hnb   = (unsigned short*)alloc((size_t)N * 128 * 2);
    unsigned short* Wh0   = (unsigned short*)alloc(256 * 128 * 2);
    unsigned short* Wl0   = (unsigned short*)alloc(256 * 128 * 2);
    unsigned short* Wh1   = (unsigned short*)alloc(256 * 128 * 2);
    unsigned short* Wl1   = (unsigned short*)alloc(256 * 128 * 2);
    unsigned short* Wh2   = (unsigned short*)alloc(128 * 128 * 2);
    unsigned short* Wl2   = (unsigned short*)alloc(128 * 128 * 2);

    // ---- adjacency build: replicated-counter fill, then per-node compaction ----
    hipMemsetAsync(cnt8, 0, (size_t)N * NREP * 4, stream);
    fill_bucket_kernel<<<(E / 4 + 255) / 256, 256, 0, stream>>>(src, dst, cnt8, slot8, E);
    compact_kernel<<<(N + 3) / 4, 256, 0, stream>>>(cnt8, slot8, dense, deg, N);

    long long total4 = (long long)N * 32;
    split_x_kernel<<<(int)((total4 + 255) / 256), 256, 0, stream>>>(x, xhi, xlo, total4);
    prep_w_all_kernel<<<320, 256, 0, stream>>>(Ws0, Wn0, Ws1, Wn1, Ws2, Wn2,
                                               Wh0, Wl0, Wh1, Wl1, Wh2, Wl2);

    const int rowTiles = (N + 63) / 64;  // 64 rows per block, block covers all cols
    const int gblocks  = (N + 3) / 4;    // one wave per node

    // ---- layer 0 ----
    mfma_dual_kernel<256><<<rowTiles, 256, 0, stream>>>(xhi, xlo, Wh0, Wl0, b0, hsb, hnb, N);
    gather_finish_kernel<128, true, true><<<gblocks, 256, 0, stream>>>(hnb, hsb, deg, dense, xhi, xlo, nullptr, N);

    // ---- layer 1 ----
    mfma_dual_kernel<256><<<rowTiles, 256, 0, stream>>>(xhi, xlo, Wh1, Wl1, b1, hsb, hnb, N);
    gather_finish_kernel<128, true, true><<<gblocks, 256, 0, stream>>>(hnb, hsb, deg, dense, xhi, xlo, nullptr, N);

    // ---- layer 2 ----
    mfma_dual_kernel<128><<<rowTiles, 256, 0, stream>>>(xhi, xlo, Wh2, Wl2, b2, hsb, hnb, N);
    gather_finish_kernel<64, false, false><<<gblocks, 256, 0, stream>>>(hnb, hsb, deg, dense, nullptr, nullptr, out, N);
}

// Round 11
// 217.752 us; speedup vs baseline: 1.2108x; 1.2108x over previous
//
#include <hip/hip_runtime.h>

#define CAP     64  // max in-degree bucket capacity (Poisson(16): P(>64) ~ 1e-21)
#define PASSES  4   // dst-range partitions for the bucket fill (L2 write locality)
#define CSTRIDE 16  // cnt padded to one counter per 64B line

typedef __attribute__((ext_vector_type(8))) short bf16x8;
typedef __attribute__((ext_vector_type(4))) float f32x4;

__device__ __forceinline__ unsigned short f2bf(float f) {
    unsigned u = __builtin_bit_cast(unsigned, f);
    u += 0x7fffu + ((u >> 16) & 1u);   // round-to-nearest-even
    return (unsigned short)(u >> 16);
}
__device__ __forceinline__ float bf2f(unsigned short h) {
    unsigned u = ((unsigned)h) << 16;
    return __builtin_bit_cast(float, u);
}

// async 16B global->LDS copy (lds dest must be wave-uniform; HW adds lane*16)
__device__ __forceinline__ void gload_lds16(const void* g, void* lds) {
    __builtin_amdgcn_global_load_lds(
        (const __attribute__((address_space(1))) void*)g,
        (__attribute__((address_space(3))) void*)lds, 16, 0, 0);
}

// ---- fill body (R8 structure: best measured 45us; queue-bound, CUs idle) ----
__device__ __forceinline__ void fill_body(int fb, int tid,
                                          const int* __restrict__ src, const int* __restrict__ dst,
                                          int* __restrict__ cnt, unsigned short* __restrict__ slot,
                                          int E, int nPerPass) {
    int t  = fb * 256 + tid;
    int e0 = t * 4;
    if (e0 >= E) return;
    int4 s4, d4;
    if (e0 + 4 <= E) {
        s4 = *reinterpret_cast<const int4*>(src + e0);
        d4 = *reinterpret_cast<const int4*>(dst + e0);
    } else {
        int r = E - e0;
        s4.x = src[e0];                   d4.x = dst[e0];
        s4.y = (r > 1) ? src[e0 + 1] : 0; d4.y = (r > 1) ? dst[e0 + 1] : -1;
        s4.z = (r > 2) ? src[e0 + 2] : 0; d4.z = (r > 2) ? dst[e0 + 2] : -1;
        s4.w = 0;                         d4.w = -1;
    }
    #pragma unroll
    for (int p = 0; p < PASSES; p++) {
        const int lo = p * nPerPass, hi = lo + nPerPass;
        if (d4.x >= lo && d4.x < hi) {
            int q = atomicAdd(&cnt[(size_t)d4.x * CSTRIDE], 1);
            if (q < CAP) slot[(size_t)d4.x * CAP + q] = (unsigned short)s4.x;
        }
        if (d4.y >= lo && d4.y < hi) {
            int q = atomicAdd(&cnt[(size_t)d4.y * CSTRIDE], 1);
            if (q < CAP) slot[(size_t)d4.y * CAP + q] = (unsigned short)s4.y;
        }
        if (d4.z >= lo && d4.z < hi) {
            int q = atomicAdd(&cnt[(size_t)d4.z * CSTRIDE], 1);
            if (q < CAP) slot[(size_t)d4.z * CAP + q] = (unsigned short)s4.z;
        }
        if (d4.w >= lo && d4.w < hi) {
            int q = atomicAdd(&cnt[(size_t)d4.w * CSTRIDE], 1);
            if (q < CAP) slot[(size_t)d4.w * CAP + q] = (unsigned short)s4.w;
        }
    }
}

// ---- MFMA dual-matmul body (R7/R8 structure) ----
// hs = h @ Ws + b (f32), hn = bf16(h @ Wn). Split-product: hh*Wh + hh*Wl + hl*Wh.
// Block = 64 rows x ALL cols; A hi/lo staged into 32KB LDS via global_load_lds;
// nibble-XOR swizzle on global source + ds_read address.
template<int DTOT>
__device__ __forceinline__ void mfma_body(int bx, int tid,
        const unsigned short* __restrict__ hhi, const unsigned short* __restrict__ hlo,
        const unsigned short* __restrict__ Wthi, const unsigned short* __restrict__ Wtlo,
        const float* __restrict__ bias, float* __restrict__ hs, unsigned short* __restrict__ hn,
        int N, unsigned short* Ahi_l, unsigned short* Alo_l)
{
    constexpr int D  = DTOT / 2;
    constexpr int NT = DTOT / 64;
    constexpr int MT = 4;
    const int wv  = tid >> 6;
    const int l   = tid & 63;
    const int lm  = l & 15;
    const int kg  = l >> 4;
    const int block0  = bx * 64;
    const int colbase = wv * (NT * 16);

    {
        const int row_l = (l >> 4);
        const int col16 = l & 15;
        #pragma unroll
        for (int i = 0; i < 4; i++) {
            const int ldsoff = wv * 4096 + i * 1024;
            int row = wv * 16 + i * 4 + row_l;
            int k2  = ((col16 ^ (row & 15)) << 4);
            int rg  = block0 + row; if (rg > N - 1) rg = N - 1;
            gload_lds16((const char*)hhi + (size_t)rg * 256 + k2, (char*)Ahi_l + ldsoff);
            gload_lds16((const char*)hlo + (size_t)rg * 256 + k2, (char*)Alo_l + ldsoff);
        }
    }
    asm volatile("s_waitcnt vmcnt(0)" ::: "memory");
    __syncthreads();

    f32x4 acc[MT][NT];
    #pragma unroll
    for (int mt = 0; mt < MT; mt++)
        #pragma unroll
        for (int nt = 0; nt < NT; nt++)
            acc[mt][nt] = (f32x4){0.f, 0.f, 0.f, 0.f};

    const size_t bofs = (size_t)(colbase + lm) * 128 + kg * 8;

    #pragma unroll
    for (int c = 0; c < 4; c++) {
        bf16x8 bh[NT], bl[NT];
        #pragma unroll
        for (int nt = 0; nt < NT; nt++) {
            const size_t bo = bofs + (size_t)nt * 16 * 128 + c * 32;
            bh[nt] = *reinterpret_cast<const bf16x8*>(Wthi + bo);
            bl[nt] = *reinterpret_cast<const bf16x8*>(Wtlo + bo);
        }
        bf16x8 ah[MT], al[MT];
        #pragma unroll
        for (int mt = 0; mt < MT; mt++) {
            const int r   = mt * 16 + lm;
            const int off = r * 128 + (((kg + 4 * c) ^ lm) << 3);
            ah[mt] = *reinterpret_cast<const bf16x8*>(&Ahi_l[off]);
            al[mt] = *reinterpret_cast<const bf16x8*>(&Alo_l[off]);
        }
        #pragma unroll
        for (int nt = 0; nt < NT; nt++)
            #pragma unroll
            for (int mt = 0; mt < MT; mt++) {
                acc[mt][nt] = __builtin_amdgcn_mfma_f32_16x16x32_bf16(ah[mt], bh[nt], acc[mt][nt], 0, 0, 0);
                acc[mt][nt] = __builtin_amdgcn_mfma_f32_16x16x32_bf16(ah[mt], bl[nt], acc[mt][nt], 0, 0, 0);
                acc[mt][nt] = __builtin_amdgcn_mfma_f32_16x16x32_bf16(al[mt], bh[nt], acc[mt][nt], 0, 0, 0);
            }
    }

    #pragma unroll
    for (int nt = 0; nt < NT; nt++) {
        const int col = colbase + nt * 16 + lm;
        const float bb = (col < D) ? bias[col] : 0.f;
        #pragma unroll
        for (int mt = 0; mt < MT; mt++) {
            #pragma unroll
            for (int i = 0; i < 4; i++) {
                int n = block0 + mt * 16 + kg * 4 + i;
                if (n >= N) continue;
                float v = acc[mt][nt][i];
                if (col < D) hs[(size_t)n * D + col] = v + bb;
                else         hn[(size_t)n * D + (col - D)] = f2bf(v);
            }
        }
    }
}

// Heterogeneous kernel: even blocks = layer-0 matmul tiles, odd blocks = bucket fill.
// mm's MFMA/LDS work occupies the CU cycles fill's atomic-queue stalls leave idle.
__global__ __launch_bounds__(256)
void mm_fill_kernel(const unsigned short* __restrict__ hhi, const unsigned short* __restrict__ hlo,
                    const unsigned short* __restrict__ Wthi, const unsigned short* __restrict__ Wtlo,
                    const float* __restrict__ bias, float* __restrict__ hs, unsigned short* __restrict__ hn,
                    int N, int nMM,
                    const int* __restrict__ src, const int* __restrict__ dst,
                    int* __restrict__ cnt, unsigned short* __restrict__ slot, int E, int nPerPass, int nFill)
{
    __shared__ unsigned short Ahi_l[64 * 128];
    __shared__ unsigned short Alo_l[64 * 128];
    const int b = blockIdx.x;
    if ((b & 1) == 0) {
        int mb = b >> 1;
        if (mb < nMM)
            mfma_body<256>(mb, threadIdx.x, hhi, hlo, Wthi, Wtlo, bias, hs, hn, N, Ahi_l, Alo_l);
    } else {
        int fb = b >> 1;
        if (fb < nFill)
            fill_body(fb, threadIdx.x, src, dst, cnt, slot, E, nPerPass);
    }
}

// Standalone matmul (layers 1, 2)
template<int DTOT>
__global__ __launch_bounds__(256)
void mfma_dual_kernel(const unsigned short* __restrict__ hhi, const unsigned short* __restrict__ hlo,
                      const unsigned short* __restrict__ Wthi, const unsigned short* __restrict__ Wtlo,
                      const float* __restrict__ bias,
                      float* __restrict__ hs, unsigned short* __restrict__ hn, int N)
{
    __shared__ unsigned short Ahi_l[64 * 128];
    __shared__ unsigned short Alo_l[64 * 128];
    mfma_body<DTOT>(blockIdx.x, threadIdx.x, hhi, hlo, Wthi, Wtlo, bias, hs, hn, N, Ahi_l, Alo_l);
}

// split_x + all-layer W prep in one launch (independent preprocessing).
__global__ __launch_bounds__(256)
void prep_kernel(const float* __restrict__ x, unsigned short* __restrict__ xhi,
                 unsigned short* __restrict__ xlo, long long total4, int splitBlocks,
                 const float* __restrict__ Ws0, const float* __restrict__ Wn0,
                 const float* __restrict__ Ws1, const float* __restrict__ Wn1,
                 const float* __restrict__ Ws2, const float* __restrict__ Wn2,
                 unsigned short* __restrict__ Wh0, unsigned short* __restrict__ Wl0,
                 unsigned short* __restrict__ Wh1, unsigned short* __restrict__ Wl1,
                 unsigned short* __restrict__ Wh2, unsigned short* __restrict__ Wl2)
{
    int b = blockIdx.x;
    if (b < splitBlocks) {
        long long i = (long long)b * 256 + threadIdx.x;
        if (i >= total4) return;
        float4 v = reinterpret_cast<const float4*>(x)[i];
        float f[4] = {v.x, v.y, v.z, v.w};
        unsigned short h4[4], l4[4];
        #pragma unroll
        for (int j = 0; j < 4; j++) {
            h4[j] = f2bf(f[j]);
            l4[j] = f2bf(f[j] - bf2f(h4[j]));
        }
        reinterpret_cast<ushort4*>(xhi)[i] = make_ushort4(h4[0], h4[1], h4[2], h4[3]);
        reinterpret_cast<ushort4*>(xlo)[i] = make_ushort4(l4[0], l4[1], l4[2], l4[3]);
        return;
    }
    b -= splitBlocks;
    const float *Ws, *Wn;
    unsigned short *Wthi, *Wtlo;
    int D, idx;
    if (b < 128)      { Ws = Ws0; Wn = Wn0; Wthi = Wh0; Wtlo = Wl0; D = 128; idx = b * 256 + threadIdx.x; }
    else if (b < 256) { Ws = Ws1; Wn = Wn1; Wthi = Wh1; Wtlo = Wl1; D = 128; idx = (b - 128) * 256 + threadIdx.x; }
    else              { Ws = Ws2; Wn = Wn2; Wthi = Wh2; Wtlo = Wl2; D = 64;  idx = (b - 256) * 256 + threadIdx.x; }
    int DT = 2 * D;
    if (idx >= 128 * DT) return;
    int k = idx / DT, col = idx % DT;
    float v = (col < D) ? Ws[k * D + col] : Wn[k * D + (col - D)];
    unsigned short hi = f2bf(v);
    unsigned short lo = f2bf(v - bf2f(hi));
    Wthi[col * 128 + k] = hi;
    Wtlo[col * 128 + k] = lo;
}

// One wave per dst node. Indices lane-resident (one coalesced 2B/lane load of the
// slot row); inner loop __shfl-broadcasts 8 indices, 8 gather loads in flight.
template<int D, bool RELU, bool SPLIT>
__global__ __launch_bounds__(256)
void gather_finish_kernel(const unsigned short* __restrict__ hn, const float* __restrict__ hs,
                          const int* __restrict__ cnt, const unsigned short* __restrict__ slot,
                          unsigned short* __restrict__ ohi, unsigned short* __restrict__ olo,
                          float* __restrict__ ofp, int N)
{
    const int node = (int)(((size_t)blockIdx.x * blockDim.x + threadIdx.x) >> 6);
    const int lane = threadIdx.x & 63;
    if (node >= N) return;

    int deg = cnt[(size_t)node * CSTRIDE];
    if (deg > CAP) deg = CAP;

    const int si = (int)slot[(size_t)node * CAP + lane];

    float p0 = 0.f, p1 = 0.f, q0 = 0.f, q1 = 0.f;
    float r0a = 0.f, r1a = 0.f, t0 = 0.f, t1 = 0.f;

    for (int j = 0; j < deg; j += 8) {
        unsigned u[8];
        bool ok[8];
        #pragma unroll
        for (int k = 0; k < 8; k++) {
            int jj = j + k;
            int s = __shfl(si, jj, 64);
            if (s > N - 1) s = N - 1;
            if (s < 0) s = 0;
            ok[k] = jj < deg;
            if constexpr (D == 128)
                u[k] = *reinterpret_cast<const unsigned*>(&hn[(size_t)s * D + lane * 2]);
            else
                u[k] = (unsigned)hn[(size_t)s * D + lane];
        }
        #pragma unroll
        for (int k = 0; k < 8; k++) {
            float f0 = ok[k] ? bf2f((unsigned short)(u[k] & 0xffffu)) : 0.f;
            if constexpr (D == 128) {
                float f1 = ok[k] ? bf2f((unsigned short)(u[k] >> 16)) : 0.f;
                switch (k & 3) {
                    case 0: p0 += f0; p1 += f1; break;
                    case 1: q0 += f0; q1 += f1; break;
                    case 2: r0a += f0; r1a += f1; break;
                    default: t0 += f0; t1 += f1; break;
                }
            } else {
                switch (k & 3) {
                    case 0: p0 += f0; break;
                    case 1: q0 += f0; break;
                    case 2: r0a += f0; break;
                    default: t0 += f0; break;
                }
            }
        }
    }
    float acc0 = (p0 + q0) + (r0a + t0);
    float acc1 = (p1 + q1) + (r1a + t1);

    const float inv = 1.0f / (float)(deg > 1 ? deg : 1);

    if constexpr (D == 128) {
        float2 s2 = *reinterpret_cast<const float2*>(&hs[(size_t)node * D + lane * 2]);
        float v0 = fmaf(acc0, inv, s2.x);
        float v1 = fmaf(acc1, inv, s2.y);
        if (RELU) { v0 = fmaxf(v0, 0.f); v1 = fmaxf(v1, 0.f); }
        if constexpr (SPLIT) {
            unsigned short h0 = f2bf(v0), h1 = f2bf(v1);
            unsigned short l0 = f2bf(v0 - bf2f(h0)), l1 = f2bf(v1 - bf2f(h1));
            *reinterpret_cast<unsigned*>(&ohi[(size_t)node * D + lane * 2]) = (unsigned)h0 | ((unsigned)h1 << 16);
            *reinterpret_cast<unsigned*>(&olo[(size_t)node * D + lane * 2]) = (unsigned)l0 | ((unsigned)l1 << 16);
        } else {
            *reinterpret_cast<float2*>(&ofp[(size_t)node * D + lane * 2]) = make_float2(v0, v1);
        }
    } else {
        float s1 = hs[(size_t)node * D + lane];
        float v = fmaf(acc0, inv, s1);
        if (RELU) v = fmaxf(v, 0.f);
        if constexpr (SPLIT) {
            unsigned short h0 = f2bf(v);
            ohi[(size_t)node * D + lane] = h0;
            olo[(size_t)node * D + lane] = f2bf(v - bf2f(h0));
        } else {
            ofp[(size_t)node * D + lane] = v;
        }
    }
}

extern "C" void kernel_launch(void* const* d_in, const int* in_sizes, int n_in,
                              void* d_out, int out_size, void* d_ws, size_t ws_size,
                              hipStream_t stream)
{
    const float* x   = (const float*)d_in[0];
    const int*   src = (const int*)d_in[1];
    const int*   dst = (const int*)d_in[2];
    const float* Ws0 = (const float*)d_in[3];
    const float* Wn0 = (const float*)d_in[4];
    const float* b0  = (const float*)d_in[5];
    const float* Ws1 = (const float*)d_in[6];
    const float* Wn1 = (const float*)d_in[7];
    const float* b1  = (const float*)d_in[8];
    const float* Ws2 = (const float*)d_in[9];
    const float* Wn2 = (const float*)d_in[10];
    const float* b2  = (const float*)d_in[11];
    float* out = (float*)d_out;

    const int N = in_sizes[0] / 128;
    const int E = in_sizes[1];

    char* ws = (char*)d_ws;
    size_t off = 0;
    auto alloc = [&](size_t bytes) -> void* {
        void* p = ws + off;
        off += (bytes + 255) & ~(size_t)255;
        return p;
    };
    int*            cnt   = (int*)           alloc((size_t)N * CSTRIDE * 4);
    unsigned short* slot  = (unsigned short*)alloc((size_t)N * CAP * 2);
    unsigned short* xhi   = (unsigned short*)alloc((size_t)N * 128 * 2);  // reused as h hi/lo between layers
    unsigned short* xlo   = (unsigned short*)alloc((size_t)N * 128 * 2);
    float*          hsb   = (float*)         alloc((size_t)N * 128 * 4);
    unsigned short* hnb   = (unsigned short*)alloc((size_t)N * 128 * 2);
    unsigned short* Wh0   = (unsigned short*)alloc(256 * 128 * 2);
    unsigned short* Wl0   = (unsigned short*)alloc(256 * 128 * 2);
    unsigned short* Wh1   = (unsigned short*)alloc(256 * 128 * 2);
    unsigned short* Wl1   = (unsigned short*)alloc(256 * 128 * 2);
    unsigned short* Wh2   = (unsigned short*)alloc(128 * 128 * 2);
    unsigned short* Wl2   = (unsigned short*)alloc(128 * 128 * 2);

    hipMemsetAsync(cnt, 0, (size_t)N * CSTRIDE * 4, stream);

    // ---- preprocessing: split x + prep all W (one launch) ----
    long long total4 = (long long)N * 32;
    const int splitBlocks = (int)((total4 + 255) / 256);
    prep_kernel<<<splitBlocks + 320, 256, 0, stream>>>(
        x, xhi, xlo, total4, splitBlocks,
        Ws0, Wn0, Ws1, Wn1, Ws2, Wn2, Wh0, Wl0, Wh1, Wl1, Wh2, Wl2);

    const int rowTiles = (N + 63) / 64;
    const int nFill    = (E / 4 + 255) / 256;
    const int nPerPass = (N + PASSES - 1) / PASSES;
    const int gblocks  = (N + 3) / 4;

    // ---- layer 0 matmul FUSED with bucket fill (hide atomic-queue stalls) ----
    {
        int nPair = rowTiles > nFill ? rowTiles : nFill;
        mm_fill_kernel<<<2 * nPair, 256, 0, stream>>>(
            xhi, xlo, Wh0, Wl0, b0, hsb, hnb, N, rowTiles,
            src, dst, cnt, slot, E, nPerPass, nFill);
    }
    gather_finish_kernel<128, true, true><<<gblocks, 256, 0, stream>>>(hnb, hsb, cnt, slot, xhi, xlo, nullptr, N);

    // ---- layer 1 ----
    mfma_dual_kernel<256><<<rowTiles, 256, 0, stream>>>(xhi, xlo, Wh1, Wl1, b1, hsb, hnb, N);
    gather_finish_kernel<128, true, true><<<gblocks, 256, 0, stream>>>(hnb, hsb, cnt, slot, xhi, xlo, nullptr, N);

    // ---- layer 2 ----
    mfma_dual_kernel<128><<<rowTiles, 256, 0, stream>>>(xhi, xlo, Wh2, Wl2, b2, hsb, hnb, N);
    gather_finish_kernel<64, false, false><<<gblocks, 256, 0, stream>>>(hnb, hsb, cnt, slot, nullptr, nullptr, out, N);
}